// Round 1
// 78.171 us; speedup vs baseline: 1.0005x; 1.0005x over previous
//
#include <hip/hip_runtime.h>
#include <hip/hip_bf16.h>

// Ball query: for each (b, p) center, collect first S point indices n with
// ||xyz[b,n] - center[b,p]||^2 < r^2 (index order), zero-fill the rest.
//
// FROZEN FP arithmetic (R6, bit-matches harness "np" ref = XLA w/ contraction):
//   cn = fma(cz,cz, fma(cy,cy, cx*cx))          (contracted mul+reduce)
//   xn = fma(z,z,   fma(y,y,   x*x))            (precomputed in pack kernel;
//                                                fp32 store/reload bit-exact)
//   dot= fma(cz,z,  fma(cy,y,  cx*x))           (ascending-K FMA)
//   d2 = (cn + xn) - 2*dot ;  valid = d2 < r2   (all fp32, strict <)
// DO NOT reorder/refactor these ops — a rounding change flips boundary masks.
//
// R19: multi-center register reuse. Scan was L2-BW-bound (~512 MB of slab
// re-reads = ~15us at 34.5 TB/s; VALU only ~6us). Each wave now serves
// C=4 consecutive centers from one 512-point register batch: traffic
// drops 4x/max-depth (~160 MB -> ~4.5us), VALU unchanged (wave-uniform
// per-center skip once cnt[i] >= S). Per-center FP sequence, scan order,
// and ballot/rank logic are bit-identical to R18.
// Blocks: 4096 = 8 batches x 512 groups; XCD-affine swizzle kept
// (blockIdx&7 = batch slab -> one XCD, slab fits its 4 MB L2).
// NO global atomics (R9: 7x regression).

typedef float f32x4 __attribute__((ext_vector_type(4)));

__global__ __launch_bounds__(256) void pack_points(
    const float* __restrict__ xyz,   // [B*N, 3]
    f32x4* __restrict__ q,           // [B*N] packed {x,y,z,xn}
    int total)
{
    const int n = blockIdx.x * blockDim.x + threadIdx.x;
    if (n >= total) return;
    const float x = xyz[(size_t)n * 3 + 0];
    const float y = xyz[(size_t)n * 3 + 1];
    const float z = xyz[(size_t)n * 3 + 2];
    // FROZEN xn sequence:
    const float xn = __builtin_fmaf(z, z,
                      __builtin_fmaf(y, y, __fmul_rn(x, x)));
    f32x4 v;
    v[0] = x; v[1] = y; v[2] = z; v[3] = xn;
    q[n] = v;
}

__global__ __launch_bounds__(64) void ball_query_wave4(
    const f32x4* __restrict__ q,          // [B*N] packed {x,y,z,xn}
    const float* __restrict__ center,     // [B, P, 3]
    const float* __restrict__ p_radius,   // [1]
    const int*   __restrict__ p_sample,   // [1]
    int* __restrict__ out,                // [B, P, S]
    int B, int N, int P)
{
    const int S = p_sample[0];
    const float r = p_radius[0];
    const float r2 = __fmul_rn(r, r);

    // XCD-affine swizzle: (blockIdx & 7) = batch slab -> XCD; remaining
    // bits pick a group of 4 consecutive centers. Requires P % 4 == 0
    // (P = 2048 in this harness).
    const int b = blockIdx.x & 7;
    const int g = blockIdx.x >> 3;         // 0 .. P/4-1
    const int c0 = b * P + g * 4;          // first of 4 centers this wave owns
    const int lane = threadIdx.x;          // 0..63

    // Per-center coords + squared norm (uniform addresses -> scalar loads)
    float cx[4], cy[4], cz[4], cn[4];
    int cnt[4];
#pragma unroll
    for (int i = 0; i < 4; ++i) {
        const size_t c = (size_t)(c0 + i);
        cx[i] = center[c * 3 + 0];
        cy[i] = center[c * 3 + 1];
        cz[i] = center[c * 3 + 2];
        // FROZEN cn sequence:
        cn[i] = __builtin_fmaf(cz[i], cz[i],
                 __builtin_fmaf(cy[i], cy[i], __fmul_rn(cx[i], cx[i])));
        cnt[i] = 0;
    }

    const f32x4* qb = q + (size_t)b * N;
    int* ob = out + (size_t)c0 * S;        // 4*S contiguous output ints

    // N = 16384 = 32 batches of 512; early exit when all 4 centers full.
    for (int n0 = 0; n0 < N; n0 += 512) {
        if (cnt[0] >= S && cnt[1] >= S && cnt[2] >= S && cnt[3] >= S) break;

        // Phase 1: 8 independent aligned dwordx4 loads — all in flight.
        f32x4 v[8];
#pragma unroll
        for (int j = 0; j < 8; ++j) {
            v[j] = qb[n0 + j * 64 + lane];
        }

        // Phase 2: per center (wave-uniform skip when full), 8 ballot
        // phases in ascending chunk order — identical order to R18.
#pragma unroll
        for (int i = 0; i < 4; ++i) {
            if (cnt[i] >= S) continue;     // uniform scalar branch
            int cc = cnt[i];
#pragma unroll
            for (int j = 0; j < 8; ++j) {
                const float x = v[j][0], y = v[j][1], z = v[j][2];
                const float xn = v[j][3]; // FROZEN xn (precomputed, bit-exact)
                // FROZEN per-pair FP sequence:
                const float dot = __builtin_fmaf(cz[i], z,
                                   __builtin_fmaf(cy[i], y, __fmul_rn(cx[i], x)));
                const float d2 = __fsub_rn(__fadd_rn(cn[i], xn),
                                           __fmul_rn(2.0f, dot));

                const bool valid = d2 < r2;
                const unsigned long long m = __ballot(valid);
                const int rank = __builtin_amdgcn_mbcnt_hi(
                    (unsigned)(m >> 32),
                    __builtin_amdgcn_mbcnt_lo((unsigned)m, 0u));
                if (valid && (cc + rank) < S) {
                    ob[i * S + cc + rank] = n0 + j * 64 + lane;
                }
                cc += __popcll(m);
            }
            cnt[i] = cc;
        }
    }

    // Zero-fill unused slots (harness poisons d_out).
#pragma unroll
    for (int i = 0; i < 4; ++i) {
        int c = cnt[i] > S ? S : cnt[i];
        for (int s = c + lane; s < S; s += 64) {
            ob[i * S + s] = 0;
        }
    }
}

extern "C" void kernel_launch(void* const* d_in, const int* in_sizes, int n_in,
                              void* d_out, int out_size, void* d_ws, size_t ws_size,
                              hipStream_t stream) {
    const float* xyz      = (const float*)d_in[0];   // [B, N, 3]
    const float* center   = (const float*)d_in[1];   // [B, P, 3]
    const float* p_radius = (const float*)d_in[2];   // scalar
    const int*   p_sample = (const int*)d_in[3];     // scalar

    const int B = 8;
    const int N = in_sizes[0] / (B * 3);   // 16384
    const int P = in_sizes[1] / (B * 3);   // 2048

    int* out = (int*)d_out;
    f32x4* q = (f32x4*)d_ws;               // B*N*16 B = 2 MB << ws_size

    // Pass 1: pack {x,y,z,xn}
    const int total = B * N;               // 131072
    pack_points<<<(total + 255) / 256, 256, 0, stream>>>(xyz, q, total);

    // Pass 2: one wave per 4 centers, XCD-affine swizzle.
    const int blocks = B * (P / 4);        // 4096
    ball_query_wave4<<<blocks, 64, 0, stream>>>(
        q, center, p_radius, p_sample, out, B, N, P);
}